// Round 1
// baseline (147.349 us; speedup 1.0000x reference)
//
#include <hip/hip_runtime.h>

// Problem constants (fixed by setup_inputs): image (1,1024,1024) f32,
// x (16,1,1024,1024) f32, W_KL (9,1,3,3) f32, b_KL (9,) f32.
// y[b,h,w] = sum_{a,d} (conv(image,W_KL)[a*3+d][h,w] + b[a*3+d]) * x[b,h+a-1,w+d-1]
#define IH 1024
#define IW 1024
#define NB 16

// Block: 64 x 8 threads. Each thread: 4 contiguous pixels of one row.
// Tile per block: 256 wide x 8 tall. Grid: (1024/256, 1024/8) = (4, 128).
__global__ __launch_bounds__(512) void fused_smblock(
    const float* __restrict__ image,
    const float* __restrict__ x,
    const float* __restrict__ Wk,
    const float* __restrict__ bk,
    float* __restrict__ out)
{
    const int tx = threadIdx.x;               // 0..63
    const int ty = threadIdx.y;               // 0..7
    const int w0 = blockIdx.x * 256 + tx * 4; // multiple of 4 -> float4 aligned
    const int h  = blockIdx.y * 8 + ty;

    // ---- conv weights / bias: uniform addresses -> compiler emits s_load ----
    float wk[81];
#pragma unroll
    for (int i = 0; i < 81; ++i) wk[i] = Wk[i];
    float bb[9];
#pragma unroll
    for (int c = 0; c < 9; ++c) bb[c] = bk[c];

    // ---- image patch rows p[a][0..5] = image[h+a-1][w0-1 .. w0+4], zero-pad ----
    float p[3][6];
#pragma unroll
    for (int a = 0; a < 3; ++a) {
        const int hh = h + a - 1;
        if (hh >= 0 && hh < IH) {
            const float* row = image + (size_t)hh * IW;
            p[a][0] = (w0 > 0) ? row[w0 - 1] : 0.f;
            const float4 m = *(const float4*)(row + w0);
            p[a][1] = m.x; p[a][2] = m.y; p[a][3] = m.z; p[a][4] = m.w;
            p[a][5] = (w0 + 4 < IW) ? row[w0 + 4] : 0.f;
        } else {
#pragma unroll
            for (int j = 0; j < 6; ++j) p[a][j] = 0.f;
        }
    }

    // ---- per-pixel kernels Kv[j][c], c = a*3+d (correlation, no flip) ----
    // Computed ONCE per pixel, amortized over the 16 batch planes.
    float Kv[4][9];
#pragma unroll
    for (int j = 0; j < 4; ++j) {
#pragma unroll
        for (int c = 0; c < 9; ++c) {
            float acc = bb[c];
#pragma unroll
            for (int i = 0; i < 3; ++i)
#pragma unroll
                for (int jj = 0; jj < 3; ++jj)
                    acc = fmaf(wk[c * 9 + i * 3 + jj], p[i][j + jj], acc);
            Kv[j][c] = acc;
        }
    }

    // ---- apply to all 16 batch planes (memory-bound streaming loop) ----
    const size_t plane = (size_t)IH * IW;
#pragma unroll 2
    for (int b = 0; b < NB; ++b) {
        const float* xp = x + (size_t)b * plane;
        float r[3][6];
#pragma unroll
        for (int a = 0; a < 3; ++a) {
            const int hh = h + a - 1;
            if (hh >= 0 && hh < IH) {
                const float* row = xp + (size_t)hh * IW;
                r[a][0] = (w0 > 0) ? row[w0 - 1] : 0.f;
                const float4 m = *(const float4*)(row + w0);
                r[a][1] = m.x; r[a][2] = m.y; r[a][3] = m.z; r[a][4] = m.w;
                r[a][5] = (w0 + 4 < IW) ? row[w0 + 4] : 0.f;
            } else {
#pragma unroll
                for (int j = 0; j < 6; ++j) r[a][j] = 0.f;
            }
        }
        float yv[4];
#pragma unroll
        for (int j = 0; j < 4; ++j) {
            float acc = 0.f;
#pragma unroll
            for (int a = 0; a < 3; ++a)
#pragma unroll
                for (int d = 0; d < 3; ++d)
                    acc = fmaf(Kv[j][a * 3 + d], r[a][j + d], acc);
            yv[j] = acc;
        }
        *(float4*)(out + (size_t)b * plane + (size_t)h * IW + w0) =
            make_float4(yv[0], yv[1], yv[2], yv[3]);
    }
}

extern "C" void kernel_launch(void* const* d_in, const int* in_sizes, int n_in,
                              void* d_out, int out_size, void* d_ws, size_t ws_size,
                              hipStream_t stream) {
    const float* image = (const float*)d_in[0]; // 1*1024*1024
    const float* x     = (const float*)d_in[1]; // 16*1*1024*1024
    const float* Wk    = (const float*)d_in[2]; // 9*1*3*3
    const float* bk    = (const float*)d_in[3]; // 9
    float* out = (float*)d_out;                 // 16*1*1024*1024 f32

    dim3 block(64, 8);
    dim3 grid(IW / 256, IH / 8); // (4, 128) = 512 blocks
    fused_smblock<<<grid, block, 0, stream>>>(image, x, Wk, bk, out);
}